// Round 1
// 650.459 us; speedup vs baseline: 1.0041x; 1.0041x over previous
//
#include <hip/hip_runtime.h>
#include <stdint.h>

// Problem constants (must match reference)
#define B_DIM 16
#define S_DIM 512
#define N_HASH 8
#define M_BLOOM 4096
#define W_WIN 2
#define K_BLOCKS (2 * W_WIN + 1)                       // 5
#define OUT_ELEMS (B_DIM * K_BLOCKS * M_BLOOM * S_DIM) // 167,772,160 floats

// Per-block slab: 64 m-rows of one batch, all 5 shift-blocks.
#define M_CHUNK 64
#define TILE_STRIDE 520                 // 4B guard + 512 data + 4B guard
#define TILE_BYTES (M_CHUNK * TILE_STRIDE)  // 33,280 B -> 4 blocks/CU

typedef float fx4 __attribute__((ext_vector_type(4)));

// One kernel, write-once, no global atomics.
//   out[b, k*M + m, s] = #{n : hashes[b, s + k - W, n] % M == m}, 0 if s+k-W OOB.
// Block = (b, m-chunk of 64). LDS holds uint8 counts tile[m][s] with 4-byte
// zero guards each side so the +/-2 shifted reads in phase 3 need no bounds
// checks (OOB s_in lands in a zeroed guard byte).
//
// Phase 3 (rewritten): one thread owns a fixed float4-column j = tid&127 and
// walks m by +2 (32 compile-time iterations). For each (m, j) it reads the 3
// LDS words covering bytes [4j-2 .. 4j+9] ONCE and emits all 5 shifted float4
// outputs via constant-shift funnel merges -> 12 B LDS read per 80 B stored
// (was 8 B per 16 B), constant-stride addresses, fully pipelineable.
__global__ __launch_bounds__(256) void bloom_window_kernel(
    const int* __restrict__ hashes, float* __restrict__ out) {
    __shared__ __align__(16) uint32_t tile32[TILE_BYTES / 4];
    uint8_t* tile = (uint8_t*)tile32;

    const int tid = threadIdx.x;
    const int b = blockIdx.x >> 6;          // 64 chunks per batch
    const int chunk = blockIdx.x & 63;
    const int m0 = chunk * M_CHUNK;

    // Phase 1: zero the tile (incl. guards), 16 B per op.
    // 2080 uint4 / 256 thr = 8.125 ea.
    uint4* t4 = (uint4*)tile32;
    for (int i = tid; i < TILE_BYTES / 16; i += 256)
        t4[i] = make_uint4(0u, 0u, 0u, 0u);
    __syncthreads();

    // Phase 2: histogram. Thread owns s-columns {2*tid, 2*tid+1} -> no LDS
    // write collisions (DS has native byte enables; different bytes of one
    // word from different lanes are safe).
    const int4* hp = (const int4*)hashes;
#pragma unroll
    for (int ss = 0; ss < 2; ++ss) {
        const int s = 2 * tid + ss;
        const int4 h01 = hp[(b * S_DIM + s) * 2 + 0];
        const int4 h23 = hp[(b * S_DIM + s) * 2 + 1];
        const int hv[8] = {h01.x, h01.y, h01.z, h01.w,
                           h23.x, h23.y, h23.z, h23.w};
#pragma unroll
        for (int n = 0; n < N_HASH; ++n) {
            const int m = hv[n] & (M_BLOOM - 1);
            const unsigned ml = (unsigned)(m - m0);
            if (ml < M_CHUNK) {
                tile[ml * TILE_STRIDE + 4 + s] += 1;
            }
        }
    }
    __syncthreads();

    // Phase 3: k-shared streaming. j fixed per thread (256 % 128 == 0), m
    // steps by 2. Wave lanes have consecutive j -> stride-1 LDS words
    // (conflict-free) and 1 KB-contiguous nontemporal dwordx4 stores per k.
    const int j = tid & 127;         // float4 index along s
    const int mb = tid >> 7;         // 0 or 1
    fx4* out4 = (fx4*)out;

    // word index of byte A = m*520 + 4j (A is 4-aligned)
    const uint32_t* wp0 = tile32 + mb * (TILE_STRIDE / 4) + j;
    // out row (k=0) = (b*5 + 0)*M + m0 + m; 128 float4 per row
    const size_t obase0 =
        ((size_t)(b * K_BLOCKS) * M_BLOOM + m0 + mb) * (S_DIM / 4) + j;

#pragma unroll 4
    for (int it = 0; it < M_CHUNK / 2; ++it) {
        const uint32_t* wp = wp0 + it * (2 * TILE_STRIDE / 4);
        const uint32_t w0 = wp[0];   // bytes A   .. A+3
        const uint32_t w1 = wp[1];   // bytes A+4 .. A+7
        const uint32_t w2 = wp[2];   // bytes A+8 .. A+11
        const size_t ob = obase0 + (size_t)(2 * it) * (S_DIM / 4);

        // packed counts for k = 0..4: bytes [A+2+k .. A+5+k]
        uint32_t p[K_BLOCKS];
        p[0] = (w0 >> 16) | (w1 << 16);
        p[1] = (w0 >> 24) | (w1 << 8);
        p[2] = w1;
        p[3] = (w1 >> 8) | (w2 << 24);
        p[4] = (w1 >> 16) | (w2 << 16);

#pragma unroll
        for (int k = 0; k < K_BLOCKS; ++k) {
            fx4 v;
            v.x = (float)(p[k] & 0xffu);
            v.y = (float)((p[k] >> 8) & 0xffu);
            v.z = (float)((p[k] >> 16) & 0xffu);
            v.w = (float)(p[k] >> 24);
            __builtin_nontemporal_store(
                v, &out4[ob + (size_t)k * (M_BLOOM * (S_DIM / 4))]);
        }
    }
}

extern "C" void kernel_launch(void* const* d_in, const int* in_sizes, int n_in,
                              void* d_out, int out_size, void* d_ws, size_t ws_size,
                              hipStream_t stream) {
    const int* hashes = (const int*)d_in[0];
    float* out = (float*)d_out;

    // 16 batches x 64 m-chunks = 1024 blocks; 33 KB LDS -> 4 blocks/CU.
    bloom_window_kernel<<<B_DIM * (M_BLOOM / M_CHUNK), 256, 0, stream>>>(hashes, out);
}